// Round 9
// baseline (11589.503 us; speedup 1.0000x reference)
//
#include <hip/hip_runtime.h>

// TreeLSTM (B=256, T=128, E=256, D=256) for MI355X / gfx950 — v7.
//
// v7 vs v6 (rocprof-driven): v6's multi-XCD persistent scan was latency-bound
// at 16.2 us/phase — per-phase FETCH 3.1 MB (A-rows replicated 8x across
// XCDs) + MALL-uncached vstk + cross-XCD barrier skew. v7 puts each
// batch-group (16 batches) on ONE CU: 16 workgroups x 1024 threads (16
// waves). All cross-wave communication is intra-workgroup -> plain global
// loads/stores + __syncthreads() (HIP memory model; NO atomics, NO MALL,
// NO fences, NO XCD assumptions). Wave w owns dims d=[16w,16w+16) of all 5
// gates = 5 full 16-col MFMA tiles (no masked tiles; all 64 lanes active in
// the cell). Floor: 16 waves x 240 MFMA x 4.85cyc = 7.8 us/phase.
// Wr_t (2.6 MB) is L2-resident (2 wgs/XCD read the same panel); A-rows read
// once per CU via L1 (16-wave reuse).
//
// Workspace layout (fixed = 87,426,048 B; no barrier page needed):
//   Wr_t  u32 [1280][512]        2,621,440 @ 0
//   Wpg   u32 [512][256]           524,288 @ 2,621,440
//   h_buf u32 [32768][256]      33,554,432 @ 3,145,728
//   c_buf f32 [32768][256]      33,554,432 @ 36,700,160
//   vstkH u32 [32][256][256]     8,388,608 @ 70,254,592   (slot 31 = zeros)
//   vstkC f32 [32][256][256]     8,388,608 @ 78,643,200
//   planL/R/W i32 [128][256]   3 x 131,072 @ 87,031,808
//   fdesc i32 [256]                  1,024 @ 87,425,024

typedef unsigned int u32;
typedef short s16x8 __attribute__((ext_vector_type(8)));
typedef float f32x4 __attribute__((ext_vector_type(4)));

#define NPAIR 128

#define MFMA16(a, b, c) __builtin_amdgcn_mfma_f32_16x16x32_bf16((a), (b), (c), 0, 0, 0)

static __device__ __forceinline__ unsigned short f2bf(float x) {
  u32 u = __builtin_bit_cast(u32, x);
  u += 0x7fffu + ((u >> 16) & 1u);  // round-to-nearest-even
  return (unsigned short)(u >> 16);
}
static __device__ __forceinline__ float bf2f(unsigned short s) {
  u32 u = ((u32)s) << 16;
  return __builtin_bit_cast(float, u);
}
static __device__ __forceinline__ u32 packhl(float x) {
  unsigned short hi = f2bf(x);
  unsigned short lo = f2bf(x - bf2f(hi));
  return ((u32)hi << 16) | (u32)lo;
}
static __device__ __forceinline__ float unpackhl(u32 p) {
  return bf2f((unsigned short)(p >> 16)) + bf2f((unsigned short)(p & 0xffffu));
}
static __device__ __forceinline__ void unpack8(uint4 a, uint4 b, s16x8 &hi, s16x8 &lo) {
  hi[0] = (short)(a.x >> 16); lo[0] = (short)a.x;
  hi[1] = (short)(a.y >> 16); lo[1] = (short)a.y;
  hi[2] = (short)(a.z >> 16); lo[2] = (short)a.z;
  hi[3] = (short)(a.w >> 16); lo[3] = (short)a.w;
  hi[4] = (short)(b.x >> 16); lo[4] = (short)b.x;
  hi[5] = (short)(b.y >> 16); lo[5] = (short)b.y;
  hi[6] = (short)(b.z >> 16); lo[6] = (short)b.z;
  hi[7] = (short)(b.w >> 16); lo[7] = (short)b.w;
}
static __device__ __forceinline__ void split8(const float *w, s16x8 &hi, s16x8 &lo) {
#pragma unroll
  for (int i = 0; i < 8; i++) {
    unsigned short h = f2bf(w[i]);
    hi[i] = (short)h;
    lo[i] = (short)f2bf(w[i] - bf2f(h));
  }
}
static __device__ __forceinline__ float sigm(float x) { return 1.0f / (1.0f + expf(-x)); }
static __device__ __forceinline__ int vslot(int code) {
  return (code & 15) * 2 + ((code >> 4) & 1);
}

// ---------------------------------------------------------------- pack
__global__ __launch_bounds__(256) void pack_kernel(
    const float *__restrict__ Wp, const float *__restrict__ Wg,
    const float *__restrict__ Wr, u32 *__restrict__ Wpg_t,
    u32 *__restrict__ Wr_t, u32 *__restrict__ vstkH, float *__restrict__ vstkC) {
  int tid = blockIdx.x * 256 + threadIdx.x;
  if (tid < 131072) {  // Wp|Wg: each [256 E][256 D]; write Wpg_t[col][k]
    int isg = tid >= 65536;
    int s = tid & 65535;
    int k = s >> 8, col = s & 255;
    float v = isg ? Wg[s] : Wp[s];
    Wpg_t[(isg ? 256 + col : col) * 256 + k] = packhl(v);
  }
  if (tid < 655360) {  // Wr [512][1280] read-linear, write Wr_t[col][k]
    int k = tid / 1280;
    int col = tid - k * 1280;
    Wr_t[col * 512 + k] = packhl(Wr[tid]);
  }
  if (tid < 65536) {  // zero value-slot 31 (ZCODE target)
    vstkH[31 * 65536 + tid] = 0u;
    vstkC[31 * 65536 + tid] = 0.0f;
  }
}

// ---------------------------------------------------------------- plan
// Straight-line register-packed symbolic stack (macros/ternaries only).
#define PGET(p, dst)                                                         \
  {                                                                          \
    u32 wsel = ((p) & 8) ? (((p) & 4) ? t3 : t2) : (((p) & 4) ? t1 : t0);    \
    dst = (int)((wsel >> (((p) & 3) * 8)) & 0xffu);                          \
  }
#define PSET(p, e)                                                           \
  {                                                                          \
    u32 sh_ = (u32)((p) & 3) * 8u;                                           \
    u32 m_ = ~(0xffu << sh_);                                                \
    u32 nv_ = ((u32)(e)) << sh_;                                             \
    int w_ = (p) >> 2;                                                       \
    t0 = (w_ == 0) ? ((t0 & m_) | nv_) : t0;                                 \
    t1 = (w_ == 1) ? ((t1 & m_) | nv_) : t1;                                 \
    t2 = (w_ == 2) ? ((t2 & m_) | nv_) : t2;                                 \
    t3 = (w_ == 3) ? ((t3 & m_) | nv_) : t3;                                 \
  }
#define PDOSTEP(tr, l, r, w)                                                 \
  {                                                                          \
    if ((tr) == 0) {                                                         \
      int pos_ = min(ptr, 15);                                               \
      PSET(pos_, (u32)(bptr & 127));                                         \
      ptr++;                                                                 \
      bptr--;                                                                \
    } else {                                                                 \
      int pl_ = min(max(ptr - 2, 0), 15);                                    \
      int pr_ = min(max(ptr - 1, 0), 15);                                    \
      PGET(pl_, l);                                                          \
      PGET(pr_, r);                                                          \
      u32 v_ = ((verb >> pl_) & 1u) ^ 1u;                                    \
      verb = (verb & ~(1u << pl_)) | (v_ << pl_);                            \
      PSET(pl_, 0x80u | (v_ << 4) | (u32)pl_);                               \
      w = pl_ * 2 + (int)v_;                                                 \
      ptr--;                                                                 \
    }                                                                        \
  }

__global__ __launch_bounds__(256) void plan_kernel(
    const int *__restrict__ trans, int *__restrict__ pL, int *__restrict__ pR,
    int *__restrict__ pW, int *__restrict__ fdesc) {
  int b = threadIdx.x;
  u32 t0 = 0x9F9F9F9Fu, t1 = 0x9F9F9F9Fu, t2 = 0x9F9F9F9Fu, t3 = 0x9F9F9F9Fu;
  u32 verb = 0;
  int ptr = 0, bptr = 127;

  for (int f = 0; f < NPAIR; ++f) {
    int trA = trans[(2 * f) * 256 + b];
    int trB = (2 * f + 1 < 255) ? trans[(2 * f + 1) * 256 + b] : -1;
    int l = 0x9F, r = 0x9F, w = -1;
    PDOSTEP(trA, l, r, w);
    if (trB >= 0) PDOSTEP(trB, l, r, w);
    pL[f * 256 + b] = (l & 0x80) ? (0x8000 | (l & 0x1f)) : l;
    pR[f * 256 + b] = (r & 0x80) ? (0x8000 | (r & 0x1f)) : r;
    pW[f * 256 + b] = w;
  }
  int pf = min(max(ptr - 1, 0), 15);
  int fd;
  PGET(pf, fd);
  fdesc[b] = (fd & 0x80) ? (0x8000 | (fd & 0x1f)) : fd;
}

// ---------------------------------------------------------------- front GEMM
__global__ __launch_bounds__(64) void front_kernel(
    const float *__restrict__ x, const u32 *__restrict__ Wpg,
    const float *__restrict__ bp, const float *__restrict__ bg,
    u32 *__restrict__ h_buf, float *__restrict__ c_buf) {
  const int lane = threadIdx.x;
  const int rbase = blockIdx.x * 16;
  const int y = blockIdx.y;  // 0..3 -> d cols [y*64, y*64+64)
  const int rlo = lane & 15;
  const int khi = (lane >> 4) * 8;

  f32x4 z = {0.f, 0.f, 0.f, 0.f};
  f32x4 aP[4], aG[4];
#pragma unroll
  for (int i = 0; i < 4; i++) { aP[i] = z; aG[i] = z; }

#pragma unroll 2
  for (int kt = 0; kt < 8; ++kt) {
    int k = kt * 32 + khi;
    s16x8 Ah, Al;
    {
      const float *ap = x + (rbase + rlo) * 256 + k;
      float4 v0 = *(const float4 *)ap;
      float4 v1 = *(const float4 *)(ap + 4);
      float w[8] = {v0.x, v0.y, v0.z, v0.w, v1.x, v1.y, v1.z, v1.w};
      split8(w, Ah, Al);
    }
#pragma unroll
    for (int nt = 0; nt < 4; ++nt) {
      int colP = y * 64 + nt * 16 + rlo;
      {
        const u32 *wp = Wpg + colP * 256 + k;
        uint4 q0 = *(const uint4 *)wp, q1 = *(const uint4 *)(wp + 4);
        s16x8 Bh, Bl;
        unpack8(q0, q1, Bh, Bl);
        aP[nt] = MFMA16(Ah, Bh, aP[nt]);
        aP[nt] = MFMA16(Ah, Bl, aP[nt]);
        aP[nt] = MFMA16(Al, Bh, aP[nt]);
      }
      {
        const u32 *wg = Wpg + (256 + colP) * 256 + k;
        uint4 q0 = *(const uint4 *)wg, q1 = *(const uint4 *)(wg + 4);
        s16x8 Bh, Bl;
        unpack8(q0, q1, Bh, Bl);
        aG[nt] = MFMA16(Ah, Bh, aG[nt]);
        aG[nt] = MFMA16(Ah, Bl, aG[nt]);
        aG[nt] = MFMA16(Al, Bh, aG[nt]);
      }
    }
  }
#pragma unroll
  for (int nt = 0; nt < 4; ++nt) {
    int d = y * 64 + nt * 16 + rlo;
    float bpd = bp[d], bgd = bg[d];
#pragma unroll
    for (int ri = 0; ri < 4; ++ri) {
      int r = rbase + (lane >> 4) * 4 + ri;
      float cv = aP[nt][ri] + bpd;
      float gv = aG[nt][ri] + bgd;
      c_buf[r * 256 + d] = cv;
      h_buf[r * 256 + d] = packhl(sigm(gv) * tanhf(cv));
    }
  }
}

// ---------------------------------------------------------------- scan
// ONE launch, grid 16 (one wg per batch-group), 1024 threads = 16 waves on
// ONE CU. Wave w owns d in [16w,16w+16) of all 5 gates (5 full MFMA tiles).
// All cross-wave deps are intra-wg: plain memory + __syncthreads().
__global__ __launch_bounds__(1024) void scan_kernel(
    const float *__restrict__ br, const u32 *__restrict__ Wr_t,
    const u32 *__restrict__ h_buf, const float *__restrict__ c_buf,
    u32 *__restrict__ vstkH, float *__restrict__ vstkC,
    const int *__restrict__ pL, const int *__restrict__ pR,
    const int *__restrict__ pW) {
  const int g = blockIdx.x;
  const int b0 = g * 16;
  const int tid = threadIdx.x;
  const int lane = tid & 63;
  const int wv = tid >> 6;  // wave 0..15
  const int dlo = lane & 15;
  const int khi = (lane >> 4) * 8;
  const int d = wv * 16 + dlo;

  // hoisted: B column bases (x512 k-stride) and biases for this lane's d
  const int bc0 = (0 * 256 + d) * 512;
  const int bc1 = (1 * 256 + d) * 512;
  const int bc2 = (2 * 256 + d) * 512;
  const int bc3 = (3 * 256 + d) * 512;
  const int bc4 = (4 * 256 + d) * 512;
  const float brI = br[d], brFl = br[256 + d], brFr = br[512 + d];
  const float brG = br[768 + d], brO = br[1024 + d];
  const int myb = b0 + dlo;  // A-row batch for this lane

  for (int f = 0; f < NPAIR; ++f) {
    const int fb = f * 256 + b0;
    const int lc = pL[fb + dlo];
    const int rc = pR[fb + dlo];
    const int w = pW[fb + dlo];

    if (__ballot(w >= 0) != 0ull) {
      const u32 *srcL = (lc & 0x8000)
                            ? vstkH + ((vslot(lc) * 256 + myb) << 8)
                            : h_buf + (((myb << 7) + (lc & 127)) << 8);
      const u32 *srcR = (rc & 0x8000)
                            ? vstkH + ((vslot(rc) * 256 + myb) << 8)
                            : h_buf + (((myb << 7) + (rc & 127)) << 8);

      f32x4 acc0 = {0.f, 0.f, 0.f, 0.f};
      f32x4 acc1 = acc0, acc2 = acc0, acc3 = acc0, acc4 = acc0;

#define SCAN_KT(SRC, KOFF)                                                   \
  {                                                                          \
    const u32 *s = (SRC) + kt * 32 + khi;                                    \
    uint4 a0 = *(const uint4 *)s, a1 = *(const uint4 *)(s + 4);              \
    s16x8 Ah, Al;                                                            \
    unpack8(a0, a1, Ah, Al);                                                 \
    const int kk = (KOFF) + kt * 32 + khi;                                   \
    {                                                                        \
      const u32 *wp = Wr_t + bc0 + kk;                                       \
      uint4 q0 = *(const uint4 *)wp, q1 = *(const uint4 *)(wp + 4);          \
      s16x8 Bh, Bl;                                                          \
      unpack8(q0, q1, Bh, Bl);                                               \
      acc0 = MFMA16(Ah, Bh, acc0);                                           \
      acc0 = MFMA16(Ah, Bl, acc0);                                           \
      acc0 = MFMA16(Al, Bh, acc0);                                           \
    }                                                                        \
    {                                                                        \
      const u32 *wp = Wr_t + bc1 + kk;                                       \
      uint4 q0 = *(const uint4 *)wp, q1 = *(const uint4 *)(wp + 4);          \
      s16x8 Bh, Bl;                                                          \
      unpack8(q0, q1, Bh, Bl);                                               \
      acc1 = MFMA16(Ah, Bh, acc1);                                           \
      acc1 = MFMA16(Ah, Bl, acc1);                                           \
      acc1 = MFMA16(Al, Bh, acc1);                                           \
    }                                                                        \
    {                                                                        \
      const u32 *wp = Wr_t + bc2 + kk;                                       \
      uint4 q0 = *(const uint4 *)wp, q1 = *(const uint4 *)(wp + 4);          \
      s16x8 Bh, Bl;                                                          \
      unpack8(q0, q1, Bh, Bl);                                               \
      acc2 = MFMA16(Ah, Bh, acc2);                                           \
      acc2 = MFMA16(Ah, Bl, acc2);                                           \
      acc2 = MFMA16(Al, Bh, acc2);                                           \
    }                                                                        \
    {                                                                        \
      const u32 *wp = Wr_t + bc3 + kk;                                       \
      uint4 q0 = *(const uint4 *)wp, q1 = *(const uint4 *)(wp + 4);          \
      s16x8 Bh, Bl;                                                          \
      unpack8(q0, q1, Bh, Bl);                                               \
      acc3 = MFMA16(Ah, Bh, acc3);                                           \
      acc3 = MFMA16(Ah, Bl, acc3);                                           \
      acc3 = MFMA16(Al, Bh, acc3);                                           \
    }                                                                        \
    {                                                                        \
      const u32 *wp = Wr_t + bc4 + kk;                                       \
      uint4 q0 = *(const uint4 *)wp, q1 = *(const uint4 *)(wp + 4);          \
      s16x8 Bh, Bl;                                                          \
      unpack8(q0, q1, Bh, Bl);                                               \
      acc4 = MFMA16(Ah, Bh, acc4);                                           \
      acc4 = MFMA16(Ah, Bl, acc4);                                           \
      acc4 = MFMA16(Al, Bh, acc4);                                           \
    }                                                                        \
  }

#pragma unroll 4
      for (int kt = 0; kt < 8; ++kt) SCAN_KT(srcL, 0)
#pragma unroll 4
      for (int kt = 0; kt < 8; ++kt) SCAN_KT(srcR, 256)
#undef SCAN_KT

      // cell: acc{0..4}[ri] = gates {i,f_l,f_r,g,o} for batch
      // b2 = b0+(lane>>4)*4+ri at dim d. All 64 lanes active.
#pragma unroll
      for (int ri = 0; ri < 4; ++ri) {
        const int rr = (lane >> 4) * 4 + ri;
        const int w2 = pW[fb + rr];
        if (w2 >= 0) {
          const int b2 = b0 + rr;
          const int lc2 = pL[fb + rr];
          const int rc2 = pR[fb + rr];
          float c_l = (lc2 & 0x8000)
                          ? vstkC[(vslot(lc2) * 256 + b2) * 256 + d]
                          : c_buf[(b2 * 128 + (lc2 & 127)) * 256 + d];
          float c_r = (rc2 & 0x8000)
                          ? vstkC[(vslot(rc2) * 256 + b2) * 256 + d]
                          : c_buf[(b2 * 128 + (rc2 & 127)) * 256 + d];
          float ii = acc0[ri] + brI;
          float fl = acc1[ri] + brFl;
          float fr = acc2[ri] + brFr;
          float gg = acc3[ri] + brG;
          float oo = acc4[ri] + brO;
          float cv = sigm(ii) * tanhf(gg) + sigm(fl) * c_l + sigm(fr) * c_r;
          float hv = sigm(oo) * tanhf(cv);
          vstkH[(w2 * 256 + b2) * 256 + d] = packhl(hv);
          vstkC[(w2 * 256 + b2) * 256 + d] = cv;
        }
      }
    }
    __syncthreads();  // phase boundary: writes visible wg-wide (same CU)
  }
}

// ---------------------------------------------------------------- output
__global__ __launch_bounds__(256) void out_kernel(
    const int *__restrict__ fdesc, const u32 *__restrict__ h_buf,
    const u32 *__restrict__ vstkH, float *__restrict__ out) {
  int tid = blockIdx.x * 256 + threadIdx.x;  // 65536
  int b = tid >> 8, d = tid & 255;
  int code = fdesc[b];
  u32 hv = (code & 0x8000)
               ? vstkH[(vslot(code) * 256 + b) * 256 + d]
               : h_buf[(b * 128 + (code & 127)) * 256 + d];
  out[tid] = unpackhl(hv);
}

// ---------------------------------------------------------------- launch
extern "C" void kernel_launch(void *const *d_in, const int *in_sizes, int n_in,
                              void *d_out, int out_size, void *d_ws, size_t ws_size,
                              hipStream_t stream) {
  const float *x = (const float *)d_in[0];
  const float *Wp = (const float *)d_in[1];
  const float *bp = (const float *)d_in[2];
  const float *Wg = (const float *)d_in[3];
  const float *bg = (const float *)d_in[4];
  const float *Wr = (const float *)d_in[5];
  const float *br = (const float *)d_in[6];
  const int *trans = (const int *)d_in[7];
  float *out = (float *)d_out;

  char *ws = (char *)d_ws;
  u32 *Wr_t = (u32 *)(ws);
  u32 *Wpg = (u32 *)(ws + 2621440);
  u32 *h_buf = (u32 *)(ws + 3145728);
  float *c_buf = (float *)(ws + 36700160);
  u32 *vstkH = (u32 *)(ws + 70254592);
  float *vstkC = (float *)(ws + 78643200);
  int *planL = (int *)(ws + 87031808);
  int *planR = (int *)(ws + 87162880);
  int *planW = (int *)(ws + 87293952);
  int *fdesc = (int *)(ws + 87425024);

  pack_kernel<<<2560, 256, 0, stream>>>(Wp, Wg, Wr, Wpg, Wr_t, vstkH, vstkC);
  plan_kernel<<<1, 256, 0, stream>>>(trans, planL, planR, planW, fdesc);
  front_kernel<<<dim3(2048, 4), 64, 0, stream>>>(x, Wpg, bp, bg, h_buf, c_buf);
  scan_kernel<<<16, 1024, 0, stream>>>(br, Wr_t, h_buf, c_buf, vstkH, vstkC,
                                       planL, planR, planW);
  out_kernel<<<256, 256, 0, stream>>>(fdesc, h_buf, vstkH, out);
}